// Round 3
// baseline (492.184 us; speedup 1.0000x reference)
//
#include <hip/hip_runtime.h>

#define TTOK  2048
#define HID   2048
#define IMID  768
#define NEXP  16
#define NPAIR 4096
#define NSLOT 4224          // 4096 + 128 slack
#define BM    128
#define MAXT  48            // max tiles: 15 + 4096/128 = 47
#define HBUF  4096          // one half-K buffer: 128 rows x 32 k shorts = 8 KB

// flat conversion index space (16B units = 4 floats)
#define HS4   1048576u      // 2048*2048/4
#define GUP4  12582912u     // 16*1536*2048/4
#define DN4   6291456u      // 16*2048*768/4
#define N4TOT (HS4 + GUP4 + DN4)

typedef __attribute__((ext_vector_type(8))) short  short8;
typedef __attribute__((ext_vector_type(4))) short  bfx4;
typedef __attribute__((ext_vector_type(4))) float  floatx4;

__device__ __forceinline__ short f2bf(float f) {
    union { float f; unsigned u; } v; v.f = f;
    return (short)((v.u + 0x7FFFu + ((v.u >> 16) & 1u)) >> 16);
}

__device__ __forceinline__ void async_cp16(const void* g, void* l) {
    __builtin_amdgcn_global_load_lds(
        (const __attribute__((address_space(1))) void*)g,
        (__attribute__((address_space(3))) void*)l, 16, 0, 0);
}

// ---------- routing (block 0) + fully-coalesced fp32->bf16 convert ----------
__global__ __launch_bounds__(256) void k_pre(
    const float* __restrict__ hs, const int* __restrict__ idx,
    const float* __restrict__ tkw, const float* __restrict__ gup,
    const float* __restrict__ down, int* __restrict__ ntiles,
    int4* __restrict__ tiles, int* __restrict__ tok,
    float* __restrict__ wgt, short* __restrict__ X,
    short* __restrict__ gupb, short* __restrict__ downb)
{
    const int tid = threadIdx.x;
    if (blockIdx.x == 0) {
        __shared__ int cnt[NEXP], cur[NEXP];
        if (tid < NEXP) cnt[tid] = 0;
        __syncthreads();
        for (int i = tid; i < NPAIR; i += 256) atomicAdd(&cnt[idx[i]], 1);
        __syncthreads();
        if (tid == 0) {
            int s = 0, nt = 0;
            for (int e = 0; e < NEXP; e++) {
                cur[e] = s;
                int n = cnt[e];
                for (int tt = 0; tt * BM < n; tt++) {
                    tiles[nt] = make_int4(e, s + tt * BM, min(BM, n - tt * BM), 0);
                    nt++;
                }
                s += n;
            }
            *ntiles = nt;
        }
        __syncthreads();
        for (int i = tid; i < NPAIR; i += 256) {
            int e = idx[i];
            int p = atomicAdd(&cur[e], 1);
            tok[p] = i >> 1;
            wgt[p] = tkw[i];
        }
        for (int i = NPAIR + tid; i < NSLOT; i += 256) { tok[i] = 0; wgt[i] = 0.0f; }
        return;
    }
    // grid-stride, 16B-load/8B-store, lane-contiguous (fully coalesced)
    const unsigned nthr = (gridDim.x - 1) * 256u;
    for (unsigned u = (blockIdx.x - 1) * 256u + tid; u < N4TOT; u += nthr) {
        const float4* s; bfx4* d; unsigned off;
        if (u < HS4)              { s = (const float4*)hs;   d = (bfx4*)X;     off = u; }
        else if (u < HS4 + GUP4)  { s = (const float4*)gup;  d = (bfx4*)gupb;  off = u - HS4; }
        else                      { s = (const float4*)down; d = (bfx4*)downb; off = u - HS4 - GUP4; }
        float4 v = s[off];
        bfx4 o;
        o.x = f2bf(v.x); o.y = f2bf(v.y); o.z = f2bf(v.z); o.w = f2bf(v.w);
        d[off] = o;
    }
}

// ---------- GEMM1: X[tok] @ gate_up_bf16^T -> silu(g)*u*w -> mid (bf16) ----------
// 4-deep half-K (K=32) ring pipeline, one barrier per half-step, counted vmcnt.
__global__ __launch_bounds__(256, 2) void k_gemm1(
    const short* __restrict__ gupb, const short* __restrict__ X,
    const int* __restrict__ ntiles, const int4* __restrict__ tiles,
    const int* __restrict__ tok, const float* __restrict__ wgt,
    short* __restrict__ mid)
{
    if ((int)blockIdx.y >= *ntiles) return;
    const int4 td = tiles[blockIdx.y];
    const int e = td.x, rowstart = td.y, nvalid = td.z;
    const int ct = blockIdx.x;

    __shared__ short sA[4 * HBUF];   // 32 KB
    __shared__ short sB[4 * HBUF];   // 32 KB
    __shared__ int   s_tok[BM];
    __shared__ float s_w[BM];

    const int tid = threadIdx.x;
    if (tid < BM) { s_tok[tid] = tok[rowstart + tid]; s_w[tid] = wgt[rowstart + tid]; }
    __syncthreads();

    const int wave = tid >> 6, lane = tid & 63;
    const int m16 = lane & 15, quad = lane >> 4;

    // staging: wave w / issue j covers LDS rows (j*4+w)*16 .. +15, lane l -> row +(l>>2), k-chunk (l&3)*8
    const int srow = wave * 16 + (lane >> 2);     // 0..63
    const int kch  = (lane & 3) * 8;              // shorts
    const short* aga0 = X + (size_t)s_tok[srow]      * HID + kch;
    const short* aga1 = X + (size_t)s_tok[srow + 64] * HID + kch;
    const short* bga0 = gupb + ((size_t)e * (2 * IMID) + ct * 64 + srow) * HID + kch;          // gate
    const short* bga1 = gupb + ((size_t)e * (2 * IMID) + IMID + ct * 64 + srow) * HID + kch;   // up

    auto stage = [&](int h) {
        short* dA = sA + (h & 3) * HBUF;
        short* dB = sB + (h & 3) * HBUF;
        const int k0 = h * 32;
        async_cp16(aga0 + k0, dA + wave * 512);
        async_cp16(aga1 + k0, dA + 2048 + wave * 512);
        async_cp16(bga0 + k0, dB + wave * 512);
        async_cp16(bga1 + k0, dB + 2048 + wave * 512);
    };

    const int Wm = (wave >> 1) << 6;   // 0 / 64
    const int Wi = (wave & 1) << 5;    // 0 / 32
    floatx4 ag[4][2], au[4][2];
#pragma unroll
    for (int a = 0; a < 4; a++)
#pragma unroll
        for (int b = 0; b < 2; b++) { ag[a][b] = (floatx4)0.0f; au[a][b] = (floatx4)0.0f; }

    auto mfma_phase = [&](int c) {
        const short* A = sA + c * HBUF;
        const short* B = sB + c * HBUF;
        short8 af[4];
#pragma unroll
        for (int mf = 0; mf < 4; mf++)
            af[mf] = *(const short8*)&A[(Wm + mf * 16 + m16) * 32 + quad * 8];
#pragma unroll
        for (int nf = 0; nf < 2; nf++) {
            const short8 bg = *(const short8*)&B[(Wi + nf * 16 + m16) * 32 + quad * 8];
            const short8 bu = *(const short8*)&B[(64 + Wi + nf * 16 + m16) * 32 + quad * 8];
#pragma unroll
            for (int mf = 0; mf < 4; mf++) {
                ag[mf][nf] = __builtin_amdgcn_mfma_f32_16x16x32_bf16(af[mf], bg, ag[mf][nf], 0, 0, 0);
                au[mf][nf] = __builtin_amdgcn_mfma_f32_16x16x32_bf16(af[mf], bu, au[mf][nf], 0, 0, 0);
            }
        }
    };

    const int nh = HID / 32;   // 64 half-steps
    stage(0); stage(1); stage(2);
    for (int h = 0; h < nh - 3; ++h) {
        asm volatile("s_waitcnt vmcnt(8)" ::: "memory");
        __builtin_amdgcn_s_barrier();
        __builtin_amdgcn_sched_barrier(0);
        stage(h + 3);
        mfma_phase(h & 3);
    }
    asm volatile("s_waitcnt vmcnt(8)" ::: "memory");
    __builtin_amdgcn_s_barrier();
    __builtin_amdgcn_sched_barrier(0);
    mfma_phase((nh - 3) & 3);
    asm volatile("s_waitcnt vmcnt(4)" ::: "memory");
    __builtin_amdgcn_s_barrier();
    __builtin_amdgcn_sched_barrier(0);
    mfma_phase((nh - 2) & 3);
    asm volatile("s_waitcnt vmcnt(0)" ::: "memory");
    __builtin_amdgcn_s_barrier();
    __builtin_amdgcn_sched_barrier(0);
    mfma_phase((nh - 1) & 3);

    // epilogue: SwiGLU * router weight -> mid (bf16)
#pragma unroll
    for (int mf = 0; mf < 4; mf++) {
#pragma unroll
        for (int r = 0; r < 4; r++) {
            int m = Wm + mf * 16 + quad * 4 + r;
            if (m < nvalid) {
                float w = s_w[m];
                size_t rowp = (size_t)(rowstart + m) * IMID + ct * 64;
#pragma unroll
                for (int nf = 0; nf < 2; nf++) {
                    float g = ag[mf][nf][r], u = au[mf][nf][r];
                    float val = g / (1.0f + __expf(-g)) * u * w;
                    mid[rowp + Wi + nf * 16 + m16] = f2bf(val);
                }
            }
        }
    }
}

// ---------- GEMM2: mid @ down_bf16^T -> atomicAdd into out ----------
__global__ __launch_bounds__(256, 2) void k_gemm2(
    const short* __restrict__ downb, const short* __restrict__ mid,
    const int* __restrict__ ntiles, const int4* __restrict__ tiles,
    const int* __restrict__ tok, float* __restrict__ out)
{
    if ((int)blockIdx.y >= *ntiles) return;
    const int4 td = tiles[blockIdx.y];
    const int e = td.x, rowstart = td.y, nvalid = td.z;
    const int ct = blockIdx.x;

    __shared__ short sA[4 * HBUF];
    __shared__ short sB[4 * HBUF];
    __shared__ int   s_tok[BM];

    const int tid = threadIdx.x;
    if (tid < BM) s_tok[tid] = tok[rowstart + tid];
    __syncthreads();

    const int wave = tid >> 6, lane = tid & 63;
    const int m16 = lane & 15, quad = lane >> 4;

    const int srow = wave * 16 + (lane >> 2);
    const int kch  = (lane & 3) * 8;
    const short* aga0 = mid + (size_t)(rowstart + srow)      * IMID + kch;
    const short* aga1 = mid + (size_t)(rowstart + srow + 64) * IMID + kch;
    const short* bga0 = downb + ((size_t)e * HID + ct * 128 + srow) * IMID + kch;
    const short* bga1 = downb + ((size_t)e * HID + ct * 128 + 64 + srow) * IMID + kch;

    auto stage = [&](int h) {
        short* dA = sA + (h & 3) * HBUF;
        short* dB = sB + (h & 3) * HBUF;
        const int k0 = h * 32;
        async_cp16(aga0 + k0, dA + wave * 512);
        async_cp16(aga1 + k0, dA + 2048 + wave * 512);
        async_cp16(bga0 + k0, dB + wave * 512);
        async_cp16(bga1 + k0, dB + 2048 + wave * 512);
    };

    const int Wm = (wave >> 1) << 6;
    const int Wn = (wave & 1) << 6;   // 0 / 64 over the 128 H-cols
    floatx4 acc[4][4];
#pragma unroll
    for (int a = 0; a < 4; a++)
#pragma unroll
        for (int b = 0; b < 4; b++) acc[a][b] = (floatx4)0.0f;

    auto mfma_phase = [&](int c) {
        const short* A = sA + c * HBUF;
        const short* B = sB + c * HBUF;
        short8 af[4];
#pragma unroll
        for (int mf = 0; mf < 4; mf++)
            af[mf] = *(const short8*)&A[(Wm + mf * 16 + m16) * 32 + quad * 8];
#pragma unroll
        for (int nf = 0; nf < 4; nf++) {
            const short8 bf_ = *(const short8*)&B[(Wn + nf * 16 + m16) * 32 + quad * 8];
#pragma unroll
            for (int mf = 0; mf < 4; mf++)
                acc[mf][nf] = __builtin_amdgcn_mfma_f32_16x16x32_bf16(af[mf], bf_, acc[mf][nf], 0, 0, 0);
        }
    };

    const int nh = IMID / 32;  // 24 half-steps
    stage(0); stage(1); stage(2);
    for (int h = 0; h < nh - 3; ++h) {
        asm volatile("s_waitcnt vmcnt(8)" ::: "memory");
        __builtin_amdgcn_s_barrier();
        __builtin_amdgcn_sched_barrier(0);
        stage(h + 3);
        mfma_phase(h & 3);
    }
    asm volatile("s_waitcnt vmcnt(8)" ::: "memory");
    __builtin_amdgcn_s_barrier();
    __builtin_amdgcn_sched_barrier(0);
    mfma_phase((nh - 3) & 3);
    asm volatile("s_waitcnt vmcnt(4)" ::: "memory");
    __builtin_amdgcn_s_barrier();
    __builtin_amdgcn_sched_barrier(0);
    mfma_phase((nh - 2) & 3);
    asm volatile("s_waitcnt vmcnt(0)" ::: "memory");
    __builtin_amdgcn_s_barrier();
    __builtin_amdgcn_sched_barrier(0);
    mfma_phase((nh - 1) & 3);

#pragma unroll
    for (int mf = 0; mf < 4; mf++) {
#pragma unroll
        for (int r = 0; r < 4; r++) {
            int m = Wm + mf * 16 + quad * 4 + r;
            if (m < nvalid) {
                int t = s_tok[m];
                float* op = out + (size_t)t * HID + ct * 128;
#pragma unroll
                for (int nf = 0; nf < 4; nf++)
                    atomicAdd(op + Wn + nf * 16 + m16, acc[mf][nf][r]);
            }
        }
    }
}

// ---------- launch ----------
extern "C" void kernel_launch(void* const* d_in, const int* in_sizes, int n_in,
                              void* d_out, int out_size, void* d_ws, size_t ws_size,
                              hipStream_t stream) {
    const float* hs   = (const float*)d_in[0];
    const int*   idx  = (const int*)d_in[1];
    const float* tkw  = (const float*)d_in[2];
    const float* gup  = (const float*)d_in[3];
    const float* down = (const float*)d_in[4];
    float* out = (float*)d_out;

    char* ws = (char*)d_ws;
    int*   ntiles = (int*)ws;
    int4*  tiles  = (int4*)(ws + 16);
    int*   tok    = (int*)(ws + 1024);
    float* wgt    = (float*)(ws + 1024 + NSLOT * 4);
    short* mid    = (short*)(ws + 36864);
    short* X      = (short*)(ws + 36864 + (size_t)NSLOT * IMID * 2);
    short* gupb   = (short*)(ws + (16u << 20));                         // 16 MiB
    short* downb  = (short*)(ws + (16u << 20) + (size_t)NEXP * 2 * IMID * HID * 2);

    hipMemsetAsync(d_out, 0, (size_t)TTOK * HID * sizeof(float), stream);
    k_pre  <<<2049, 256, 0, stream>>>(
        hs, idx, tkw, gup, down, ntiles, tiles, tok, wgt, X, gupb, downb);
    k_gemm1<<<dim3(IMID / 64, MAXT), 256, 0, stream>>>(gupb, X, ntiles, tiles, tok, wgt, mid);
    k_gemm2<<<dim3(HID / 128, MAXT), 256, 0, stream>>>(downb, mid, ntiles, tiles, tok, out);
}